// Round 2
// baseline (177.983 us; speedup 1.0000x reference)
//
#include <hip/hip_runtime.h>
#include <stdint.h>

#define NTETS   200000
#define FEATS   128
#define OUTF    128
#define NG      5
#define BM      128
#define NTHR    512
#define NBLOCKS ((NTETS + BM - 1) / BM)

typedef __attribute__((ext_vector_type(8))) short  short8v;
typedef __attribute__((ext_vector_type(4))) float  f32x4;

static __device__ __forceinline__ unsigned short bf16_rne(float f) {
  union { float f; unsigned u; } v; v.f = f;
  unsigned r = v.u + 0x7FFFu + ((v.u >> 16) & 1u);
  return (unsigned short)(r >> 16);
}

// Detect int64-vs-int32 storage of neighbor indices (deterministic for fixed input).
__global__ void detect_mode_k(const int* __restrict__ nbr, int* __restrict__ flag) {
  int t = threadIdx.x;
  int nz = 0;
  for (int i = t; i < 4096; i += 64) nz |= nbr[2 * i + 1];
  unsigned long long any = __ballot(nz != 0);
  if (t == 0) flag[0] = (any == 0ULL) ? 1 : 0;   // 1 => int64 indices
}

// W fp32 [128][640] -> bf16 image, same linear layout (elementwise convert).
__global__ void prep_w_k(const float* __restrict__ W, unsigned short* __restrict__ wimg) {
  int id = blockIdx.x * 256 + threadIdx.x;
  if (id < OUTF * NG * FEATS) wimg[id] = bf16_rne(W[id]);
}

static __device__ __forceinline__ void cvt_write(char* buf, int sr, int sh, int aswz,
                                                 const f32x4* st) {
#pragma unroll
  for (int j = 0; j < 4; ++j) {
    f32x4 f0 = st[2 * j], f1 = st[2 * j + 1];
    short8v v;
    v[0] = (short)bf16_rne(f0[0]); v[1] = (short)bf16_rne(f0[1]);
    v[2] = (short)bf16_rne(f0[2]); v[3] = (short)bf16_rne(f0[3]);
    v[4] = (short)bf16_rne(f1[0]); v[5] = (short)bf16_rne(f1[1]);
    v[6] = (short)bf16_rne(f1[2]); v[7] = (short)bf16_rne(f1[3]);
    *(short8v*)(buf + sr * 256 + (((sh << 6) + (j << 4)) ^ aswz)) = v;
  }
}

__global__ __launch_bounds__(NTHR, 4) void conv_mfma_k(
    const float* __restrict__ feat, const int* __restrict__ nbr,
    const float* __restrict__ bias, const unsigned short* __restrict__ wimg,
    const int* __restrict__ mode, float* __restrict__ out)
{
  __shared__ __align__(16) char lds[2 * 32768];   // A tiles only, double-buffered
  const int t    = threadIdx.x;
  const int row0 = blockIdx.x * BM;
  const int lane = t & 63;
  const int wv   = t >> 6;          // 8 waves
  const int wm   = wv >> 2;         // 0..1 : 64-row slab
  const int wn   = wv & 3;          // 0..3 : 32-col slab
  const int lr   = lane & 15;
  const int lk   = lane >> 4;

  // staging role: 4 threads per row, 128B (32 floats) each
  const int sr = t >> 2;
  const int sh = t & 3;
  const int gr = row0 + sr;
  const bool valid = gr < NTETS;
  const bool m64 = (mode[0] != 0);

  int srcs[NG];
  srcs[0] = valid ? gr : 0;
  {
    long b4 = (long)gr * 4;
#pragma unroll
    for (int q = 0; q < 4; ++q) {
      int s = valid ? (m64 ? nbr[2 * (b4 + q)] : nbr[b4 + q]) : 0;
      srcs[q + 1] = ((unsigned)s < (unsigned)NTETS) ? s : 0;
    }
  }

  const int aswz = (sr & 7) << 4;   // staging-write swizzle
  const int rswz = (lr & 7) << 4;   // fragment-read swizzle
  // per-lane base into bf16 W image: row (wn*32+lr), k-offset lk*8
  const unsigned short* wbase = wimg + (size_t)(wn * 32 + lr) * (NG * FEATS) + lk * 8;

  const f32x4 zero = {0.f, 0.f, 0.f, 0.f};
  f32x4 acc[4][2];
#pragma unroll
  for (int i = 0; i < 4; ++i) { acc[i][0] = zero; acc[i][1] = zero; }

  f32x4 st[8];
  // ---- prologue: stage chunk 0 into buf0 ----
  {
    const f32x4* s = (const f32x4*)(feat + (size_t)srcs[0] * FEATS + sh * 32);
#pragma unroll
    for (int j = 0; j < 8; ++j) st[j] = s[j];
    cvt_write(lds, sr, sh, aswz, st);
  }
  __syncthreads();

  for (int g = 0; g < NG; ++g) {
    // issue next chunk's gathered loads EARLY (hide under compute)
    if (g + 1 < NG) {
      const f32x4* s = (const f32x4*)(feat + (size_t)srcs[g + 1] * FEATS + sh * 32);
#pragma unroll
      for (int j = 0; j < 8; ++j) st[j] = s[j];
    }
    // compute chunk g: K=128 = 4 steps of K=32
    const char* abuf = lds + (g & 1) * 32768;
#pragma unroll
    for (int kk = 0; kk < 4; ++kk) {
      short8v a[4], b[2];
#pragma unroll
      for (int ms = 0; ms < 4; ++ms)
        a[ms] = *(const short8v*)(abuf + (wm * 64 + ms * 16 + lr) * 256 +
                                  (((kk << 6) + (lk << 4)) ^ rswz));
#pragma unroll
      for (int ns = 0; ns < 2; ++ns)
        b[ns] = *(const short8v*)(wbase + ns * 16 * (NG * FEATS) + g * FEATS + kk * 32);
#pragma unroll
      for (int ms = 0; ms < 4; ++ms)
#pragma unroll
        for (int ns = 0; ns < 2; ++ns)
          acc[ms][ns] = __builtin_amdgcn_mfma_f32_16x16x32_bf16(a[ms], b[ns], acc[ms][ns], 0, 0, 0);
    }
    // write-late: convert + ds_write next chunk into the other buffer
    if (g + 1 < NG)
      cvt_write(lds + ((g + 1) & 1) * 32768, sr, sh, aswz, st);
    __syncthreads();
  }

  // ---- epilogue: bias + relu + fp32 store (C: col=l&15, row=(l>>4)*4+reg) ----
#pragma unroll
  for (int ns = 0; ns < 2; ++ns) {
    const int col = wn * 32 + ns * 16 + lr;
    const float bv = bias[col];
#pragma unroll
    for (int ms = 0; ms < 4; ++ms) {
      const int rbase = row0 + wm * 64 + ms * 16 + lk * 4;
#pragma unroll
      for (int i = 0; i < 4; ++i) {
        int r = rbase + i;
        if (r < NTETS) {
          float vv = acc[ms][ns][i] + bv;
          out[(size_t)r * OUTF + col] = vv > 0.f ? vv : 0.f;
        }
      }
    }
  }
}

extern "C" void kernel_launch(void* const* d_in, const int* in_sizes, int n_in,
                              void* d_out, int out_size, void* d_ws, size_t ws_size,
                              hipStream_t stream) {
  const float* feat = (const float*)d_in[0];
  const int*   nbr  = (const int*)d_in[1];
  const float* W    = (const float*)d_in[2];
  const float* bias = (const float*)d_in[3];
  float* out = (float*)d_out;

  int* mode = (int*)d_ws;
  unsigned short* wimg = (unsigned short*)((char*)d_ws + 1024);

  detect_mode_k<<<1, 64, 0, stream>>>(nbr, mode);
  prep_w_k<<<320, 256, 0, stream>>>(W, wimg);
  conv_mfma_k<<<NBLOCKS, NTHR, 0, stream>>>(feat, nbr, bias, wimg, mode, out);
}

// Round 3
// 142.348 us; speedup vs baseline: 1.2503x; 1.2503x over previous
//
#include <hip/hip_runtime.h>
#include <stdint.h>

#define NTETS   200000
#define FEATS   128
#define OUTF    128
#define NG      5
#define BM      128
#define NTHR    512
#define NBLOCKS ((NTETS + BM - 1) / BM)

typedef __attribute__((ext_vector_type(8))) short     short8v;
typedef __attribute__((ext_vector_type(4))) float     f32x4;
typedef __attribute__((ext_vector_type(2))) unsigned  uint2v;

static __device__ __forceinline__ unsigned short bf16_rne(float f) {
  union { float f; unsigned u; } v; v.f = f;
  unsigned r = v.u + 0x7FFFu + ((v.u >> 16) & 1u);
  return (unsigned short)(r >> 16);
}

// round-half-up bf16 pack of two floats -> one u32 (lo = a, hi = b)
static __device__ __forceinline__ unsigned pack_bf16x2(float a, float b) {
  union { float f; unsigned u; } x, y; x.f = a; y.f = b;
  return ((x.u + 0x8000u) >> 16) | ((y.u + 0x8000u) & 0xFFFF0000u);
}

// Detect int64-vs-int32 storage of neighbor indices (deterministic for fixed input).
__global__ void detect_mode_k(const int* __restrict__ nbr, int* __restrict__ flag) {
  int t = threadIdx.x;
  int nz = 0;
  for (int i = t; i < 4096; i += 64) nz |= nbr[2 * i + 1];
  unsigned long long any = __ballot(nz != 0);
  if (t == 0) flag[0] = (any == 0ULL) ? 1 : 0;   // 1 => int64 indices
}

// W fp32 [128][640] -> bf16 image, same linear layout.
__global__ void prep_w_k(const float* __restrict__ W, unsigned short* __restrict__ wimg) {
  int id = blockIdx.x * 256 + threadIdx.x;
  if (id < OUTF * NG * FEATS) wimg[id] = bf16_rne(W[id]);
}

__global__ __launch_bounds__(NTHR, 4) void conv_mfma_k(
    const float* __restrict__ feat, const int* __restrict__ nbr,
    const float* __restrict__ bias, const unsigned short* __restrict__ wimg,
    const int* __restrict__ mode, float* __restrict__ out)
{
  __shared__ __align__(16) char albuf[2][32768];   // A tiles, double-buffered
  __shared__ int rowsrc[NG][BM];

  const int t    = threadIdx.x;
  const int row0 = blockIdx.x * BM;
  const int lane = t & 63;
  const int wv   = t >> 6;          // 8 waves
  const int wm   = wv >> 2;         // 0..1 : 64-row slab
  const int wn   = wv & 3;          // 0..3 : 32-col slab
  const int lr   = lane & 15;
  const int lk   = lane >> 4;

  // ---- fill rowsrc[5][128] once ----
  {
    const bool m64 = (mode[0] != 0);
    int r = t >> 2, q = t & 3;
    int gr = row0 + r;
    bool valid = gr < NTETS;
    if (q == 0) rowsrc[0][r] = valid ? gr : 0;
    int s = 0;
    if (valid) {
      size_t idx = (size_t)gr * 4 + q;
      s = m64 ? nbr[2 * idx] : nbr[idx];
    }
    rowsrc[q + 1][r] = (valid && (unsigned)s < (unsigned)NTETS) ? s : 0;
  }
  __syncthreads();

  // staging lane geometry: 16-lane group stages one row-half (256B contiguous) per instr
  const int sgrp = lane >> 4;   // which of 4 rows in a group
  const int scol = lane & 15;   // 16B unit within a half-row

  const f32x4 zero = {0.f, 0.f, 0.f, 0.f};
  f32x4 acc[4][2];
#pragma unroll
  for (int i = 0; i < 4; ++i) { acc[i][0] = zero; acc[i][1] = zero; }

  f32x4 stA[4][2];
  short8v b[4][2];

  // ---- prologue: stage chunk 0 into buf0 ----
#pragma unroll
  for (int i = 0; i < 4; ++i) {
    int r = wv * 16 + i * 4 + sgrp;
    int src = rowsrc[0][r];
    const float* p = feat + (size_t)src * FEATS;
    stA[i][0] = *(const f32x4*)(p + scol * 4);        // bytes [scol*16, +16)
    stA[i][1] = *(const f32x4*)(p + 64 + scol * 4);   // second half-row
  }
#pragma unroll
  for (int i = 0; i < 4; ++i) {
    int r = wv * 16 + i * 4 + sgrp;
    int swz = (r & 7) << 4;
#pragma unroll
    for (int h = 0; h < 2; ++h) {
      uint2v wq;
      wq[0] = pack_bf16x2(stA[i][h][0], stA[i][h][1]);
      wq[1] = pack_bf16x2(stA[i][h][2], stA[i][h][3]);
      *(uint2v*)(albuf[0] + r * 256 + ((h * 128 + scol * 8) ^ swz)) = wq;
    }
  }
  __syncthreads();

  const int rswz = (lr & 7) << 4;
  const unsigned short* wb = wimg + (size_t)(wn * 32 + lr) * (NG * FEATS) + lk * 8;

#pragma unroll 1
  for (int g = 0; g < NG; ++g) {
    // B-fragment loads FIRST (oldest in vmcnt order -> waiting on them
    // leaves the A-prefetch loads in flight)
#pragma unroll
    for (int kk = 0; kk < 4; ++kk)
#pragma unroll
      for (int ns = 0; ns < 2; ++ns)
        b[kk][ns] = *(const short8v*)(wb + (size_t)ns * 16 * (NG * FEATS) +
                                      g * FEATS + kk * 32);
    // A-prefetch for next chunk: fully-contiguous 256B half-row instructions
    if (g + 1 < NG) {
#pragma unroll
      for (int i = 0; i < 4; ++i) {
        int r = wv * 16 + i * 4 + sgrp;
        int src = rowsrc[g + 1][r];
        const float* p = feat + (size_t)src * FEATS;
        stA[i][0] = *(const f32x4*)(p + scol * 4);
        stA[i][1] = *(const f32x4*)(p + 64 + scol * 4);
      }
    }
    __builtin_amdgcn_sched_barrier(0);   // pin: loads issued before compute

    const char* abuf = albuf[g & 1];
#pragma unroll
    for (int kk = 0; kk < 4; ++kk) {
      short8v a[4];
#pragma unroll
      for (int ms = 0; ms < 4; ++ms)
        a[ms] = *(const short8v*)(abuf + (wm * 64 + ms * 16 + lr) * 256 +
                                  (((kk << 6) + (lk << 4)) ^ rswz));
#pragma unroll
      for (int ms = 0; ms < 4; ++ms)
#pragma unroll
        for (int ns = 0; ns < 2; ++ns)
          acc[ms][ns] = __builtin_amdgcn_mfma_f32_16x16x32_bf16(
              a[ms], b[kk][ns], acc[ms][ns], 0, 0, 0);
    }

    // write-late: convert + swizzled ds_write into the other buffer
    if (g + 1 < NG) {
      char* dbuf = albuf[(g + 1) & 1];
#pragma unroll
      for (int i = 0; i < 4; ++i) {
        int r = wv * 16 + i * 4 + sgrp;
        int swz = (r & 7) << 4;
#pragma unroll
        for (int h = 0; h < 2; ++h) {
          uint2v wq;
          wq[0] = pack_bf16x2(stA[i][h][0], stA[i][h][1]);
          wq[1] = pack_bf16x2(stA[i][h][2], stA[i][h][3]);
          *(uint2v*)(dbuf + r * 256 + ((h * 128 + scol * 8) ^ swz)) = wq;
        }
      }
    }
    __syncthreads();
  }

  // ---- epilogue: bias + relu + fp32 store (C: col=l&15, row=(l>>4)*4+reg) ----
#pragma unroll
  for (int ns = 0; ns < 2; ++ns) {
    const int col = wn * 32 + ns * 16 + lr;
    const float bv = bias[col];
#pragma unroll
    for (int ms = 0; ms < 4; ++ms) {
      const int rbase = row0 + wm * 64 + ms * 16 + lk * 4;
#pragma unroll
      for (int i = 0; i < 4; ++i) {
        int r = rbase + i;
        if (r < NTETS) {
          float vv = acc[ms][ns][i] + bv;
          out[(size_t)r * OUTF + col] = vv > 0.f ? vv : 0.f;
        }
      }
    }
  }
}

extern "C" void kernel_launch(void* const* d_in, const int* in_sizes, int n_in,
                              void* d_out, int out_size, void* d_ws, size_t ws_size,
                              hipStream_t stream) {
  const float* feat = (const float*)d_in[0];
  const int*   nbr  = (const int*)d_in[1];
  const float* W    = (const float*)d_in[2];
  const float* bias = (const float*)d_in[3];
  float* out = (float*)d_out;

  int* mode = (int*)d_ws;
  unsigned short* wimg = (unsigned short*)((char*)d_ws + 1024);

  detect_mode_k<<<1, 64, 0, stream>>>(nbr, mode);
  prep_w_k<<<320, 256, 0, stream>>>(W, wimg);
  conv_mfma_k<<<NBLOCKS, NTHR, 0, stream>>>(feat, nbr, bias, wimg, mode, out);
}

// Round 4
// 140.492 us; speedup vs baseline: 1.2669x; 1.0132x over previous
//
#include <hip/hip_runtime.h>
#include <stdint.h>

#define NTETS   200000
#define FEATS   128
#define OUTF    128
#define NG      5
#define BM      128
#define NTHR    512
#define NBLOCKS ((NTETS + BM - 1) / BM)

typedef __attribute__((ext_vector_type(8))) short  short8v;
typedef __attribute__((ext_vector_type(4))) float  f32x4;

static __device__ __forceinline__ unsigned short bf16_rne(float f) {
  union { float f; unsigned u; } v; v.f = f;
  unsigned r = v.u + 0x7FFFu + ((v.u >> 16) & 1u);
  return (unsigned short)(r >> 16);
}

static __device__ __forceinline__ void gload_lds16(const void* g, void* l) {
  __builtin_amdgcn_global_load_lds(
      (const __attribute__((address_space(1))) unsigned int*)g,
      (__attribute__((address_space(3))) unsigned int*)l, 16, 0, 0);
}

// Detect int64-vs-int32 storage of neighbor indices (deterministic for fixed input).
__global__ void detect_mode_k(const int* __restrict__ nbr, int* __restrict__ flag) {
  int t = threadIdx.x;
  int nz = 0;
  for (int i = t; i < 4096; i += 64) nz |= nbr[2 * i + 1];
  unsigned long long any = __ballot(nz != 0);
  if (t == 0) flag[0] = (any == 0ULL) ? 1 : 0;   // 1 => int64 indices
}

// W fp32 [128][640] -> 5 pre-swizzled bf16 chunk images [col=128][k=128]
// (linear gload_lds dest + swizzled ds_read; verified in round 1).
__global__ void prep_w_k(const float* __restrict__ W, unsigned short* __restrict__ wimg) {
  int id = blockIdx.x * 256 + threadIdx.x;
  if (id >= NG * 128 * 128) return;
  int g = id >> 14, rem = id & 16383;
  int n = rem >> 7, k = rem & 127;
  float w = W[n * (NG * FEATS) + g * FEATS + k];
  int byteoff = (g << 15) + (n << 8) + ((k << 1) ^ ((n & 7) << 4));
  wimg[byteoff >> 1] = bf16_rne(w);
}

// features fp32 -> linear bf16 image (coalesced stream, 8 elems/thread).
__global__ __launch_bounds__(256) void prep_f_k(const float* __restrict__ feat,
                                                unsigned short* __restrict__ fimg) {
  size_t i = ((size_t)blockIdx.x * 256 + threadIdx.x) * 8;
  f32x4 a = *(const f32x4*)(feat + i);
  f32x4 b = *(const f32x4*)(feat + i + 4);
  short8v v;
  v[0] = (short)bf16_rne(a[0]); v[1] = (short)bf16_rne(a[1]);
  v[2] = (short)bf16_rne(a[2]); v[3] = (short)bf16_rne(a[3]);
  v[4] = (short)bf16_rne(b[0]); v[5] = (short)bf16_rne(b[1]);
  v[6] = (short)bf16_rne(b[2]); v[7] = (short)bf16_rne(b[3]);
  *(short8v*)(fimg + i) = v;
}

__global__ __launch_bounds__(NTHR, 2) void conv_k(
    const unsigned short* __restrict__ fimg, const int* __restrict__ nbr,
    const float* __restrict__ bias, const unsigned short* __restrict__ wimg,
    const int* __restrict__ mode, float* __restrict__ out)
{
  __shared__ __align__(16) char atile[2][32768];
  __shared__ __align__(16) char wtile[2][32768];
  __shared__ unsigned srcoff[NG][BM];

  const int t    = threadIdx.x;
  const int row0 = blockIdx.x * BM;
  const int lane = t & 63;
  const int wv   = t >> 6;          // 8 waves
  const int wm   = wv >> 2;         // 64-row slab
  const int wn   = wv & 3;          // 32-col slab
  const int lr   = lane & 15;
  const int lk   = lane >> 4;

  // ---- per-block source byte-offsets into fimg ----
  {
    const bool m64 = (mode[0] != 0);
    for (int e = t; e < NG * BM; e += NTHR) {
      int g = e >> 7, r = e & (BM - 1);
      int gr = row0 + r;
      int s = 0;
      if (gr < NTETS) {
        if (g == 0) s = gr;
        else {
          size_t idx = (size_t)gr * 4 + (g - 1);
          s = m64 ? nbr[2 * idx] : nbr[idx];
          if ((unsigned)s >= (unsigned)NTETS) s = 0;
        }
      }
      srcoff[g][r] = (unsigned)s * 256u;
    }
  }
  __syncthreads();

  const int arow_lo = lane >> 4;            // row-within-quad
  const unsigned apos = (unsigned)((lane & 15) << 4);

  // A: wave stages its 16 rows, 4 instrs x 1KB; LDS dest linear, swizzle on SOURCE addr.
#define ISSUE_A(g_, buf_) do {                                                  \
    _Pragma("unroll")                                                           \
    for (int i_ = 0; i_ < 4; ++i_) {                                            \
      int r_ = wv * 16 + i_ * 4 + arow_lo;                                      \
      unsigned o_ = srcoff[g_][r_] + (apos ^ (unsigned)((r_ & 7) << 4));        \
      gload_lds16((const char*)fimg + o_, &atile[buf_][wv * 4096 + i_ * 1024]); \
    }                                                                           \
  } while (0)

  // W: linear 4KB copy per wave from pre-swizzled chunk image.
#define ISSUE_W(g_, buf_) do {                                                  \
    const char* ws_ = (const char*)wimg + ((g_) << 15) + wv * 4096 + (lane << 4); \
    _Pragma("unroll")                                                           \
    for (int i_ = 0; i_ < 4; ++i_)                                              \
      gload_lds16(ws_ + i_ * 1024, &wtile[buf_][wv * 4096 + i_ * 1024]);        \
  } while (0)

  // ---- prologue: 2-deep DMA pipeline ----
  ISSUE_A(0, 0); ISSUE_W(0, 0);
  ISSUE_A(1, 1); ISSUE_W(1, 1);
  asm volatile("s_waitcnt vmcnt(8)" ::: "memory");   // chunk 0 landed
  __builtin_amdgcn_sched_barrier(0);
  __builtin_amdgcn_s_barrier();

  const f32x4 zero = {0.f, 0.f, 0.f, 0.f};
  f32x4 acc[4][2];
#pragma unroll
  for (int i = 0; i < 4; ++i) { acc[i][0] = zero; acc[i][1] = zero; }

  const int rswz  = (lr & 7) << 4;
  const int abase = (wm * 64 + lr) * 256;
  const int bbase = (wn * 32 + lr) * 256;

#pragma unroll
  for (int g = 0; g < NG; ++g) {
    const int bi = g & 1;
    short8v a[4][4], b[4][2];
#pragma unroll
    for (int kk = 0; kk < 4; ++kk) {
      const int ko = ((kk << 6) + (lk << 4)) ^ rswz;
#pragma unroll
      for (int ms = 0; ms < 4; ++ms)
        a[kk][ms] = *(const short8v*)(&atile[bi][abase + ms * 4096 + ko]);
#pragma unroll
      for (int ns = 0; ns < 2; ++ns)
        b[kk][ns] = *(const short8v*)(&wtile[bi][bbase + ns * 4096 + ko]);
    }
    asm volatile("s_waitcnt lgkmcnt(0)" ::: "memory");  // frags in regs
    __builtin_amdgcn_sched_barrier(0);
    __builtin_amdgcn_s_barrier();                        // buf bi free for reuse
    if (g + 2 < NG) { ISSUE_A(g + 2, bi); ISSUE_W(g + 2, bi); }
    __builtin_amdgcn_sched_barrier(0);
#pragma unroll
    for (int kk = 0; kk < 4; ++kk)
#pragma unroll
      for (int ms = 0; ms < 4; ++ms)
#pragma unroll
        for (int ns = 0; ns < 2; ++ns)
          acc[ms][ns] = __builtin_amdgcn_mfma_f32_16x16x32_bf16(
              a[kk][ms], b[kk][ns], acc[ms][ns], 0, 0, 0);
    if (g + 1 < NG) {
      if (g + 2 < NG) asm volatile("s_waitcnt vmcnt(8)" ::: "memory"); // g+1 landed, g+2 in flight
      else            asm volatile("s_waitcnt vmcnt(0)" ::: "memory"); // drain last
      __builtin_amdgcn_sched_barrier(0);
      __builtin_amdgcn_s_barrier();
    }
  }

  // ---- epilogue: bias + relu + fp32 store (C: col=l&15, row=(l>>4)*4+reg) ----
#pragma unroll
  for (int ns = 0; ns < 2; ++ns) {
    const int col = wn * 32 + ns * 16 + lr;
    const float bv = bias[col];
#pragma unroll
    for (int ms = 0; ms < 4; ++ms) {
      const int rbase = row0 + wm * 64 + ms * 16 + lk * 4;
#pragma unroll
      for (int i = 0; i < 4; ++i) {
        int r = rbase + i;
        if (r < NTETS) {
          float vv = acc[ms][ns][i] + bv;
          out[(size_t)r * OUTF + col] = vv > 0.f ? vv : 0.f;
        }
      }
    }
  }
}

extern "C" void kernel_launch(void* const* d_in, const int* in_sizes, int n_in,
                              void* d_out, int out_size, void* d_ws, size_t ws_size,
                              hipStream_t stream) {
  const float* feat = (const float*)d_in[0];
  const int*   nbr  = (const int*)d_in[1];
  const float* W    = (const float*)d_in[2];
  const float* bias = (const float*)d_in[3];
  float* out = (float*)d_out;

  int* mode = (int*)d_ws;
  unsigned short* wimg = (unsigned short*)((char*)d_ws + 1024);          // 160 KB
  unsigned short* fimg = (unsigned short*)((char*)d_ws + 165888);        // 51.2 MB

  detect_mode_k<<<1, 64, 0, stream>>>(nbr, mode);
  prep_w_k<<<320, 256, 0, stream>>>(W, wimg);
  prep_f_k<<<(NTETS * FEATS / 8 + 255) / 256, 256, 0, stream>>>(feat, fimg);
  conv_k<<<NBLOCKS, NTHR, 0, stream>>>(fimg, nbr, bias, wimg, mode, out);
}

// Round 5
// 128.126 us; speedup vs baseline: 1.3891x; 1.0965x over previous
//
#include <hip/hip_runtime.h>
#include <stdint.h>

#define NTETS   200000
#define FEATS   128
#define OUTF    128
#define NG      5
#define BM      128
#define NTHR    512
#define NBLOCKS ((NTETS + BM - 1) / BM)

typedef __attribute__((ext_vector_type(8))) short  short8v;
typedef __attribute__((ext_vector_type(4))) float  f32x4;

static __device__ __forceinline__ unsigned short bf16_rne(float f) {
  union { float f; unsigned u; } v; v.f = f;
  unsigned r = v.u + 0x7FFFu + ((v.u >> 16) & 1u);
  return (unsigned short)(r >> 16);
}

static __device__ __forceinline__ void gload_lds16(const void* g, void* l) {
  __builtin_amdgcn_global_load_lds(
      (const __attribute__((address_space(1))) unsigned int*)g,
      (__attribute__((address_space(3))) unsigned int*)l, 16, 0, 0);
}

// Detect int64-vs-int32 storage of neighbor indices (deterministic for fixed input).
__global__ void detect_mode_k(const int* __restrict__ nbr, int* __restrict__ flag) {
  int t = threadIdx.x;
  int nz = 0;
  for (int i = t; i < 4096; i += 64) nz |= nbr[2 * i + 1];
  unsigned long long any = __ballot(nz != 0);
  if (t == 0) flag[0] = (any == 0ULL) ? 1 : 0;   // 1 => int64 indices
}

// W fp32 [128][640] -> fragment-ordered bf16 image [g][kk][wn][ns][lr][lk][8],
// so a wave's B-fragment load is one contiguous, coalesced 1 KB block (L2-hot).
__global__ void prep_wfrag_k(const float* __restrict__ W, unsigned short* __restrict__ wf) {
  int id = blockIdx.x * 256 + threadIdx.x;
  if (id >= NG * 16384) return;
  int e  = id & 7;
  int lk = (id >> 3) & 3;
  int lr = (id >> 5) & 15;
  int ns = (id >> 9) & 1;
  int wn = (id >> 10) & 3;
  int kk = (id >> 12) & 3;
  int g  = id >> 14;
  int n = wn * 32 + ns * 16 + lr;
  int k = g * 128 + kk * 32 + lk * 8 + e;
  wf[id] = bf16_rne(W[n * (NG * FEATS) + k]);
}

// features fp32 -> linear bf16 image (coalesced stream, 8 elems/thread).
__global__ __launch_bounds__(256) void prep_f_k(const float* __restrict__ feat,
                                                unsigned short* __restrict__ fimg) {
  size_t i = ((size_t)blockIdx.x * 256 + threadIdx.x) * 8;
  f32x4 a = *(const f32x4*)(feat + i);
  f32x4 b = *(const f32x4*)(feat + i + 4);
  short8v v;
  v[0] = (short)bf16_rne(a[0]); v[1] = (short)bf16_rne(a[1]);
  v[2] = (short)bf16_rne(a[2]); v[3] = (short)bf16_rne(a[3]);
  v[4] = (short)bf16_rne(b[0]); v[5] = (short)bf16_rne(b[1]);
  v[6] = (short)bf16_rne(b[2]); v[7] = (short)bf16_rne(b[3]);
  *(short8v*)(fimg + i) = v;
}

__global__ __launch_bounds__(NTHR, 4) void conv_k(
    const unsigned short* __restrict__ fimg, const int* __restrict__ nbr,
    const float* __restrict__ bias, const unsigned short* __restrict__ wf,
    const int* __restrict__ mode, float* __restrict__ out)
{
  __shared__ __align__(16) char atile[2][32768];   // A tiles only, double-buffered
  __shared__ unsigned srcoff[NG][BM];

  const int t    = threadIdx.x;
  const int row0 = blockIdx.x * BM;
  const int lane = t & 63;
  const int wv   = t >> 6;          // 8 waves
  const int wm   = wv >> 2;         // 64-row slab
  const int wn   = wv & 3;          // 32-col slab
  const int lr   = lane & 15;
  const int lk   = lane >> 4;

  // ---- per-block source byte-offsets into fimg ----
  {
    const bool m64 = (mode[0] != 0);
    for (int e = t; e < NG * BM; e += NTHR) {
      int g = e >> 7, r = e & (BM - 1);
      int gr = row0 + r;
      int s = 0;
      if (gr < NTETS) {
        if (g == 0) s = gr;
        else {
          size_t idx = (size_t)gr * 4 + (g - 1);
          s = m64 ? nbr[2 * idx] : nbr[idx];
          if ((unsigned)s >= (unsigned)NTETS) s = 0;
        }
      }
      srcoff[g][r] = (unsigned)s * 256u;
    }
  }
  __syncthreads();

  const int arow_lo = lane >> 4;
  const unsigned apos = (unsigned)((lane & 15) << 4);

#define ISSUE_A(g_, buf_) do {                                                  \
    _Pragma("unroll")                                                           \
    for (int i_ = 0; i_ < 4; ++i_) {                                            \
      int r_ = wv * 16 + i_ * 4 + arow_lo;                                      \
      unsigned o_ = srcoff[g_][r_] + (apos ^ (unsigned)((r_ & 7) << 4));        \
      gload_lds16((const char*)fimg + o_, &atile[buf_][wv * 4096 + i_ * 1024]); \
    }                                                                           \
  } while (0)

  // ---- prologue: 2-deep A-DMA pipeline ----
  ISSUE_A(0, 0);
  ISSUE_A(1, 1);
  asm volatile("s_waitcnt vmcnt(4)" ::: "memory");   // chunk 0 landed, chunk 1 in flight
  __builtin_amdgcn_sched_barrier(0);
  __builtin_amdgcn_s_barrier();

  const f32x4 zero = {0.f, 0.f, 0.f, 0.f};
  f32x4 acc[4][2];
#pragma unroll
  for (int i = 0; i < 4; ++i) { acc[i][0] = zero; acc[i][1] = zero; }

  const int rswz  = (lr & 7) << 4;
  const int abase = (wm * 64 + lr) * 256;
  // per-lane base into fragment-ordered W image (wn and lane terms folded in)
  const char* wfl = (const char*)wf + (size_t)(wn * 2) * 1024 + lr * 64 + lk * 16;

#define LOADA(dst_, kk_) do {                                                   \
    _Pragma("unroll")                                                           \
    for (int ms_ = 0; ms_ < 4; ++ms_)                                           \
      dst_[ms_] = *(const short8v*)(&atile[bi][abase + ms_ * 4096 +             \
                                    ((((kk_) << 6) + (lk << 4)) ^ rswz)]);      \
  } while (0)

#define FMA8(aset_, kk_) do {                                                   \
    _Pragma("unroll")                                                           \
    for (int ms_ = 0; ms_ < 4; ++ms_)                                           \
      _Pragma("unroll")                                                         \
      for (int ns_ = 0; ns_ < 2; ++ns_)                                         \
        acc[ms_][ns_] = __builtin_amdgcn_mfma_f32_16x16x32_bf16(                \
            aset_[ms_], b[kk_][ns_], acc[ms_][ns_], 0, 0, 0);                   \
  } while (0)

#pragma unroll
  for (int g = 0; g < NG; ++g) {
    const int bi = g & 1;
    // B-fragments: 8 coalesced 1KB loads from L2-hot fragment image
    short8v b[4][2];
#pragma unroll
    for (int kk = 0; kk < 4; ++kk)
#pragma unroll
      for (int ns = 0; ns < 2; ++ns)
        b[kk][ns] = *(const short8v*)(wfl + (size_t)((g * 4 + kk) * 8 + ns) * 1024);
    __builtin_amdgcn_sched_barrier(0);   // pin B issue before the ds_read phase

    short8v a0[4], a1[4];
    LOADA(a0, 0);
    LOADA(a1, 1);
    FMA8(a0, 0);
    LOADA(a0, 2);
    FMA8(a1, 1);
    LOADA(a1, 3);
    FMA8(a0, 2);
    if (g + 2 < NG) {            // all waves done reading buf bi -> safe to overwrite
      asm volatile("s_waitcnt lgkmcnt(0)" ::: "memory");
      __builtin_amdgcn_sched_barrier(0);
      __builtin_amdgcn_s_barrier();
      ISSUE_A(g + 2, bi);
    }
    FMA8(a1, 3);
    if (g + 1 < NG) {            // publish A(g+1) before next iteration reads it
      if (g + 2 < NG) asm volatile("s_waitcnt vmcnt(4)" ::: "memory");
      else            asm volatile("s_waitcnt vmcnt(0)" ::: "memory");
      __builtin_amdgcn_sched_barrier(0);
      __builtin_amdgcn_s_barrier();
    }
  }

  // ---- epilogue: bias + relu + fp32 store (C: col=l&15, row=(l>>4)*4+reg) ----
#pragma unroll
  for (int ns = 0; ns < 2; ++ns) {
    const int col = wn * 32 + ns * 16 + lr;
    const float bv = bias[col];
#pragma unroll
    for (int ms = 0; ms < 4; ++ms) {
      const int rbase = row0 + wm * 64 + ms * 16 + lk * 4;
#pragma unroll
      for (int i = 0; i < 4; ++i) {
        int r = rbase + i;
        if (r < NTETS) {
          float vv = acc[ms][ns][i] + bv;
          out[(size_t)r * OUTF + col] = vv > 0.f ? vv : 0.f;
        }
      }
    }
  }
#undef ISSUE_A
#undef LOADA
#undef FMA8
}

extern "C" void kernel_launch(void* const* d_in, const int* in_sizes, int n_in,
                              void* d_out, int out_size, void* d_ws, size_t ws_size,
                              hipStream_t stream) {
  const float* feat = (const float*)d_in[0];
  const int*   nbr  = (const int*)d_in[1];
  const float* W    = (const float*)d_in[2];
  const float* bias = (const float*)d_in[3];
  float* out = (float*)d_out;

  int* mode = (int*)d_ws;
  unsigned short* wf   = (unsigned short*)((char*)d_ws + 1024);       // 160 KB frag image
  unsigned short* fimg = (unsigned short*)((char*)d_ws + 164864);     // 51.2 MB bf16 features

  detect_mode_k<<<1, 64, 0, stream>>>(nbr, mode);
  prep_wfrag_k<<<320, 256, 0, stream>>>(W, wf);
  prep_f_k<<<(NTETS * FEATS / 8 + 255) / 256, 256, 0, stream>>>(feat, fimg);
  conv_k<<<NBLOCKS, NTHR, 0, stream>>>(fimg, nbr, bias, wf, mode, out);
}

// Round 6
// 116.323 us; speedup vs baseline: 1.5301x; 1.1015x over previous
//
#include <hip/hip_runtime.h>
#include <stdint.h>

#define NTETS   200000
#define FEATS   128
#define OUTF    128
#define NG      5
#define BM      128
#define NTHR    512
#define NBLOCKS ((NTETS + BM - 1) / BM)

typedef __attribute__((ext_vector_type(8))) short  short8v;
typedef __attribute__((ext_vector_type(4))) float  f32x4;

static __device__ __forceinline__ unsigned short bf16_rne(float f) {
  union { float f; unsigned u; } v; v.f = f;
  unsigned r = v.u + 0x7FFFu + ((v.u >> 16) & 1u);
  return (unsigned short)(r >> 16);
}

// Detect int64-vs-int32 storage of neighbor indices (deterministic for fixed input).
__global__ void detect_mode_k(const int* __restrict__ nbr, int* __restrict__ flag) {
  int t = threadIdx.x;
  int nz = 0;
  for (int i = t; i < 4096; i += 64) nz |= nbr[2 * i + 1];
  unsigned long long any = __ballot(nz != 0);
  if (t == 0) flag[0] = (any == 0ULL) ? 1 : 0;   // 1 => int64 indices
}

// W fp32 [128][640] -> fragment-ordered bf16 image [g][kk][wn][ns][lr][lk][8].
__global__ void prep_wfrag_k(const float* __restrict__ W, unsigned short* __restrict__ wf) {
  int id = blockIdx.x * 256 + threadIdx.x;
  if (id >= NG * 16384) return;
  int e  = id & 7;
  int lk = (id >> 3) & 3;
  int lr = (id >> 5) & 15;
  int ns = (id >> 9) & 1;
  int wn = (id >> 10) & 3;
  int kk = (id >> 12) & 3;
  int g  = id >> 14;
  int n = wn * 32 + ns * 16 + lr;
  int k = g * 128 + kk * 32 + lk * 8 + e;
  wf[id] = bf16_rne(W[n * (NG * FEATS) + k]);
}

// features fp32 -> linear bf16 image (coalesced stream, 8 elems/thread).
__global__ __launch_bounds__(256) void prep_f_k(const float* __restrict__ feat,
                                                unsigned short* __restrict__ fimg) {
  size_t i = ((size_t)blockIdx.x * 256 + threadIdx.x) * 8;
  f32x4 a = *(const f32x4*)(feat + i);
  f32x4 b = *(const f32x4*)(feat + i + 4);
  short8v v;
  v[0] = (short)bf16_rne(a[0]); v[1] = (short)bf16_rne(a[1]);
  v[2] = (short)bf16_rne(a[2]); v[3] = (short)bf16_rne(a[3]);
  v[4] = (short)bf16_rne(b[0]); v[5] = (short)bf16_rne(b[1]);
  v[6] = (short)bf16_rne(b[2]); v[7] = (short)bf16_rne(b[3]);
  *(short8v*)(fimg + i) = v;
}

__global__ __launch_bounds__(NTHR, 4) void conv_k(
    const unsigned short* __restrict__ fimg, const int* __restrict__ nbr,
    const float* __restrict__ bias, const unsigned short* __restrict__ wf,
    const int* __restrict__ mode, float* __restrict__ out)
{
  __shared__ __align__(16) char atile[2][32768];   // A tiles only, double-buffered
  __shared__ unsigned srcoff[NG][BM];

  const int t    = threadIdx.x;
  const int row0 = blockIdx.x * BM;
  const int lane = t & 63;
  const int wv   = t >> 6;          // 8 waves
  const int wm   = wv >> 2;         // 64-row slab
  const int wn   = wv & 3;          // 32-col slab
  const int lr   = lane & 15;
  const int lk   = lane >> 4;

  // ---- per-block source byte-offsets into fimg ----
  {
    const bool m64 = (mode[0] != 0);
    for (int e = t; e < NG * BM; e += NTHR) {
      int g = e >> 7, r = e & (BM - 1);
      int gr = row0 + r;
      int s = 0;
      if (gr < NTETS) {
        if (g == 0) s = gr;
        else {
          size_t idx = (size_t)gr * 4 + (g - 1);
          s = m64 ? nbr[2 * idx] : nbr[idx];
          if ((unsigned)s >= (unsigned)NTETS) s = 0;
        }
      }
      srcoff[g][r] = (unsigned)s * 256u;
    }
  }
  __syncthreads();

  const int arow      = wv * 16 + (lane >> 4);     // staging row base (i adds 4)
  const unsigned apos = (unsigned)((lane & 15) << 4);

  const f32x4 zero = {0.f, 0.f, 0.f, 0.f};
  f32x4 acc[4][2];
#pragma unroll
  for (int i = 0; i < 4; ++i) { acc[i][0] = zero; acc[i][1] = zero; }

  const int rswz  = (lr & 7) << 4;
  const int abase = (wm * 64 + lr) * 256;
  const char* wfl = (const char*)wf + (size_t)(wn * 2) * 1024 + lr * 64 + lk * 16;

  short8v stA[4];
  short8v b[4][2];

  // reg-staged A gather (vector-L1 MSHR path; NOT global_load_lds)
#define GATHER_A(g_) do {                                                        \
    _Pragma("unroll")                                                            \
    for (int i_ = 0; i_ < 4; ++i_) {                                             \
      int r_ = arow + i_ * 4;                                                    \
      stA[i_] = *(const short8v*)((const char*)fimg + srcoff[g_][r_] + apos);    \
    }                                                                            \
  } while (0)

  // swizzled ds_write of staged rows into buffer buf_
#define WRITE_A(buf_) do {                                                       \
    _Pragma("unroll")                                                            \
    for (int i_ = 0; i_ < 4; ++i_) {                                             \
      int r_ = arow + i_ * 4;                                                    \
      *(short8v*)(&atile[buf_][r_ * 256 + (apos ^ (unsigned)((r_ & 7) << 4))]) = \
          stA[i_];                                                               \
    }                                                                            \
  } while (0)

#define FMA8(aset_, kk_) do {                                                    \
    _Pragma("unroll")                                                            \
    for (int ms_ = 0; ms_ < 4; ++ms_)                                            \
      _Pragma("unroll")                                                          \
      for (int ns_ = 0; ns_ < 2; ++ns_)                                          \
        acc[ms_][ns_] = __builtin_amdgcn_mfma_f32_16x16x32_bf16(                 \
            aset_[ms_], b[kk_][ns_], acc[ms_][ns_], 0, 0, 0);                    \
  } while (0)

  // ---- prologue: stage chunk 0 ----
  GATHER_A(0);
  WRITE_A(0);
  __syncthreads();

#pragma unroll
  for (int g = 0; g < NG; ++g) {
    const int bi = g & 1;
    // B(g) loads FIRST (oldest in vmcnt order -> counted wait leaves A-gathers in flight)
#pragma unroll
    for (int kk = 0; kk < 4; ++kk)
#pragma unroll
      for (int ns = 0; ns < 2; ++ns)
        b[kk][ns] = *(const short8v*)(wfl + (size_t)((g * 4 + kk) * 8 + ns) * 1024);
    // A(g+1) gathers (compile-time guard: loop is fully unrolled)
    if (g + 1 < NG) GATHER_A(g + 1);
    __builtin_amdgcn_sched_barrier(0);

    // compute chunk g
#pragma unroll
    for (int kk = 0; kk < 4; ++kk) {
      short8v a[4];
#pragma unroll
      for (int ms = 0; ms < 4; ++ms)
        a[ms] = *(const short8v*)(&atile[bi][abase + ms * 4096 +
                                  ((((kk) << 6) + (lk << 4)) ^ rswz)]);
      FMA8(a, kk);
    }
    __builtin_amdgcn_sched_barrier(0);

    // publish A(g+1) into the other buffer (compiler emits counted vmcnt for stA)
    if (g + 1 < NG) {
      WRITE_A(bi ^ 1);
      __syncthreads();
    }
  }

  // ---- epilogue: bias + relu + fp32 store (C: col=l&15, row=(l>>4)*4+reg) ----
#pragma unroll
  for (int ns = 0; ns < 2; ++ns) {
    const int col = wn * 32 + ns * 16 + lr;
    const float bv = bias[col];
#pragma unroll
    for (int ms = 0; ms < 4; ++ms) {
      const int rbase = row0 + wm * 64 + ms * 16 + lk * 4;
#pragma unroll
      for (int i = 0; i < 4; ++i) {
        int r = rbase + i;
        if (r < NTETS) {
          float vv = acc[ms][ns][i] + bv;
          out[(size_t)r * OUTF + col] = vv > 0.f ? vv : 0.f;
        }
      }
    }
  }
#undef GATHER_A
#undef WRITE_A
#undef FMA8
}

extern "C" void kernel_launch(void* const* d_in, const int* in_sizes, int n_in,
                              void* d_out, int out_size, void* d_ws, size_t ws_size,
                              hipStream_t stream) {
  const float* feat = (const float*)d_in[0];
  const int*   nbr  = (const int*)d_in[1];
  const float* W    = (const float*)d_in[2];
  const float* bias = (const float*)d_in[3];
  float* out = (float*)d_out;

  int* mode = (int*)d_ws;
  unsigned short* wf   = (unsigned short*)((char*)d_ws + 1024);       // 160 KB frag image
  unsigned short* fimg = (unsigned short*)((char*)d_ws + 164864);     // 51.2 MB bf16 features

  detect_mode_k<<<1, 64, 0, stream>>>(nbr, mode);
  prep_wfrag_k<<<320, 256, 0, stream>>>(W, wf);
  prep_f_k<<<(NTETS * FEATS / 8 + 255) / 256, 256, 0, stream>>>(feat, fimg);
  conv_k<<<NBLOCKS, NTHR, 0, stream>>>(fimg, nbr, bias, wf, mode, out);
}